// Round 3
// baseline (436.965 us; speedup 1.0000x reference)
//
#include <hip/hip_runtime.h>
#include <stdint.h>

#define B_   2
#define S_   2048
#define H_   2048
#define NH_  16
#define NKV_ 4
#define HD_  128
#define M_   (B_ * S_)   // 4096

typedef short bf16x8 __attribute__((ext_vector_type(8)));
typedef float f32x4  __attribute__((ext_vector_type(4)));
typedef float f32x16 __attribute__((ext_vector_type(16)));

__device__ __forceinline__ float b2f(unsigned short u) {
  union { unsigned int u; float f; } v; v.u = ((unsigned int)u) << 16; return v.f;
}
__device__ __forceinline__ unsigned short f2b(float f) {
  union { float f; unsigned int u; } v; v.f = f;
  unsigned int u = v.u;
  unsigned int r = (u + 0x7FFFu + ((u >> 16) & 1u)) >> 16;
  return (unsigned short)r;
}
__device__ __forceinline__ uint4 pack8(const float4& a, const float4& b) {
  uint4 r;
  r.x = (unsigned)f2b(a.x) | ((unsigned)f2b(a.y) << 16);
  r.y = (unsigned)f2b(a.z) | ((unsigned)f2b(a.w) << 16);
  r.z = (unsigned)f2b(b.x) | ((unsigned)f2b(b.y) << 16);
  r.w = (unsigned)f2b(b.z) | ((unsigned)f2b(b.w) << 16);
  return r;
}
// async global -> LDS, 16 B per lane; dest = lds base (wave-uniform) + lane*16
__device__ __forceinline__ void gload_lds(const unsigned short* g, unsigned short* l) {
  __builtin_amdgcn_global_load_lds(
      (const __attribute__((address_space(1))) unsigned int*)g,
      (__attribute__((address_space(3))) unsigned int*)l, 16, 0, 0);
}

// ---------------------------------------------------------------------------
// f32 -> bf16 bulk convert (8 elems/thread, coalesced 16B stores)
// ---------------------------------------------------------------------------
__global__ void cvt_bf16(const float* __restrict__ src, unsigned short* __restrict__ dst, int n8)
{
  int i = blockIdx.x * blockDim.x + threadIdx.x;
  if (i >= n8) return;
  const float* p = src + (size_t)i * 8;
  uint4 v = pack8(*reinterpret_cast<const float4*>(p), *reinterpret_cast<const float4*>(p + 4));
  *reinterpret_cast<uint4*>(dst + (size_t)i * 8) = v;
}

// ---------------------------------------------------------------------------
// gemm_ld: C[M,N] = A[M,K] @ B[N,K]^T, all-bf16 inputs, f32 acc.
// m97-style: 128x128 tile, BK=64, global_load_lds width=16 staging,
// XOR-swizzled LDS (chunk ^= row&7) so ds_read_b128 fragments are 2-way/bank.
// Dual-output: blockIdx.x < nxHalf -> (B0,C0) else (B1,C1). CF32: f32 C.
// ---------------------------------------------------------------------------
template<bool CF32>
__global__ __launch_bounds__(256, 4) void gemm_ld(
    const unsigned short* __restrict__ A, const unsigned short* __restrict__ B0,
    const unsigned short* __restrict__ B1, void* __restrict__ C0, void* __restrict__ C1,
    int N, int K, int nxHalf)
{
  __shared__ unsigned short As[128 * 64];   // unpadded (DMA dest must be contiguous)
  __shared__ unsigned short Bs[128 * 64];

  const unsigned short* Bm; void* Cm; int colBase;
  if ((int)blockIdx.x < nxHalf) { Bm = B0; Cm = C0; colBase = blockIdx.x * 128; }
  else                          { Bm = B1; Cm = C1; colBase = (blockIdx.x - nxHalf) * 128; }
  const int rowBase = blockIdx.y * 128;

  const int tid    = threadIdx.x;
  const int lane   = tid & 63;
  const int wid    = tid >> 6;
  const int wrow   = wid >> 1;
  const int wcol   = wid & 1;
  const int lane15 = lane & 15;
  const int quad   = lane >> 4;

  const f32x4 zero = {0.f, 0.f, 0.f, 0.f};
  f32x4 acc[4][4];
#pragma unroll
  for (int i = 0; i < 4; i++)
#pragma unroll
    for (int j = 0; j < 4; j++) acc[i][j] = zero;

  const int lr  = lane >> 3;
  const int sc8 = (lane & 7) ^ lr;      // source chunk for this lane (all issues)

  for (int kb = 0; kb < K; kb += 64) {
    __syncthreads();                    // previous compute done reading LDS
#pragma unroll
    for (int i = 0; i < 4; i++) {
      const int rg = (i * 4 + wid) * 8;
      const int r  = rg + lr;
      gload_lds(A  + (size_t)(rowBase + r) * K + kb + sc8 * 8, As + rg * 64);
      gload_lds(Bm + (size_t)(colBase + r) * K + kb + sc8 * 8, Bs + rg * 64);
    }
    __syncthreads();                    // compiler drains vmcnt(0) before barrier
#pragma unroll
    for (int kc = 0; kc < 2; kc++) {
      bf16x8 af[4], bf[4];
#pragma unroll
      for (int g = 0; g < 4; g++) {
        const int ra = wrow * 64 + g * 16 + lane15;
        const int rb = wcol * 64 + g * 16 + lane15;
        af[g] = *reinterpret_cast<const bf16x8*>(As + ra * 64 + (((kc * 4 + quad) ^ (ra & 7)) * 8));
        bf[g] = *reinterpret_cast<const bf16x8*>(Bs + rb * 64 + (((kc * 4 + quad) ^ (rb & 7)) * 8));
      }
#pragma unroll
      for (int i = 0; i < 4; i++)
#pragma unroll
        for (int j = 0; j < 4; j++)
          acc[i][j] = __builtin_amdgcn_mfma_f32_16x16x32_bf16(af[i], bf[j], acc[i][j], 0, 0, 0);
    }
  }

  if (CF32) {
    float* Cf = (float*)Cm;
#pragma unroll
    for (int i = 0; i < 4; i++) {
      int row = rowBase + wrow * 64 + i * 16 + quad * 4;
#pragma unroll
      for (int j = 0; j < 4; j++) {
        int col = colBase + wcol * 64 + j * 16 + lane15;
#pragma unroll
        for (int rr = 0; rr < 4; rr++)
          Cf[(size_t)(row + rr) * N + col] = acc[i][j][rr];
      }
    }
  } else {
    unsigned short* Cb = (unsigned short*)Cm;
#pragma unroll
    for (int i = 0; i < 4; i++) {
      int row = rowBase + wrow * 64 + i * 16 + quad * 4;
#pragma unroll
      for (int j = 0; j < 4; j++) {
        int col = colBase + wcol * 64 + j * 16 + lane15;
#pragma unroll
        for (int rr = 0; rr < 4; rr++)
          Cb[(size_t)(row + rr) * N + col] = f2b(acc[i][j][rr]);
      }
    }
  }
}

// ---------------------------------------------------------------------------
// Fallback GEMM (round-8 proven): VGPR-roundtrip staging, f32 B packed at load.
// ---------------------------------------------------------------------------
template<bool OPROJ>
__global__ __launch_bounds__(256, 3) void gemm_k(
    const void* __restrict__ A, const float* __restrict__ B0, const float* __restrict__ B1,
    void* __restrict__ C0, void* __restrict__ C1, int N, int K, int nxHalf)
{
  __shared__ unsigned short As[128 * 72];
  __shared__ unsigned short Bs[128 * 72];

  const float* Bm; void* Cm; int colBase;
  if ((int)blockIdx.x < nxHalf) { Bm = B0; Cm = C0; colBase = blockIdx.x * 128; }
  else                          { Bm = B1; Cm = C1; colBase = (blockIdx.x - nxHalf) * 128; }
  const int rowBase = blockIdx.y * 128;

  const int tid    = threadIdx.x;
  const int lane   = tid & 63;
  const int wid    = tid >> 6;
  const int wrow   = wid >> 1;
  const int wcol   = wid & 1;
  const int lane15 = lane & 15;
  const int quad   = lane >> 4;

  const f32x4 zero = {0.f, 0.f, 0.f, 0.f};
  f32x4 acc[4][4];
#pragma unroll
  for (int i = 0; i < 4; i++)
#pragma unroll
    for (int j = 0; j < 4; j++) acc[i][j] = zero;

  const int r0 = tid >> 3;
  const int c8 = tid & 7;

  uint4 av[4], bv[4];
#pragma unroll
  for (int p = 0; p < 4; p++) {
    int r = r0 + 32 * p;
    if (OPROJ) {
      av[p] = *reinterpret_cast<const uint4*>((const unsigned short*)A + (size_t)(rowBase + r) * K + c8 * 8);
    } else {
      const float* pA = (const float*)A + (size_t)(rowBase + r) * K + c8 * 8;
      av[p] = pack8(*reinterpret_cast<const float4*>(pA), *reinterpret_cast<const float4*>(pA + 4));
    }
    const float* pB = Bm + (size_t)(colBase + r) * K + c8 * 8;
    bv[p] = pack8(*reinterpret_cast<const float4*>(pB), *reinterpret_cast<const float4*>(pB + 4));
  }

  for (int kb = 0; kb < K; kb += 64) {
    __syncthreads();
#pragma unroll
    for (int p = 0; p < 4; p++) {
      int r = r0 + 32 * p;
      *reinterpret_cast<uint4*>(As + r * 72 + c8 * 8) = av[p];
      *reinterpret_cast<uint4*>(Bs + r * 72 + c8 * 8) = bv[p];
    }
    __syncthreads();
    const int kn = kb + 64;
    if (kn < K) {
#pragma unroll
      for (int p = 0; p < 4; p++) {
        int r = r0 + 32 * p;
        if (OPROJ) {
          av[p] = *reinterpret_cast<const uint4*>((const unsigned short*)A + (size_t)(rowBase + r) * K + kn + c8 * 8);
        } else {
          const float* pA = (const float*)A + (size_t)(rowBase + r) * K + kn + c8 * 8;
          av[p] = pack8(*reinterpret_cast<const float4*>(pA), *reinterpret_cast<const float4*>(pA + 4));
        }
        const float* pB = Bm + (size_t)(colBase + r) * K + kn + c8 * 8;
        bv[p] = pack8(*reinterpret_cast<const float4*>(pB), *reinterpret_cast<const float4*>(pB + 4));
      }
    }
#pragma unroll
    for (int kc = 0; kc < 2; kc++) {
      bf16x8 af[4], bf[4];
#pragma unroll
      for (int g = 0; g < 4; g++) {
        af[g] = *reinterpret_cast<const bf16x8*>(As + (wrow * 64 + g * 16 + lane15) * 72 + kc * 32 + quad * 8);
        bf[g] = *reinterpret_cast<const bf16x8*>(Bs + (wcol * 64 + g * 16 + lane15) * 72 + kc * 32 + quad * 8);
      }
#pragma unroll
      for (int i = 0; i < 4; i++)
#pragma unroll
        for (int j = 0; j < 4; j++)
          acc[i][j] = __builtin_amdgcn_mfma_f32_16x16x32_bf16(af[i], bf[j], acc[i][j], 0, 0, 0);
    }
  }

  if (OPROJ) {
    float* Cf = (float*)Cm;
#pragma unroll
    for (int i = 0; i < 4; i++) {
      int row = rowBase + wrow * 64 + i * 16 + quad * 4;
#pragma unroll
      for (int j = 0; j < 4; j++) {
        int col = colBase + wcol * 64 + j * 16 + lane15;
#pragma unroll
        for (int rr = 0; rr < 4; rr++)
          Cf[(size_t)(row + rr) * N + col] = acc[i][j][rr];
      }
    }
  } else {
    unsigned short* Cb = (unsigned short*)Cm;
#pragma unroll
    for (int i = 0; i < 4; i++) {
      int row = rowBase + wrow * 64 + i * 16 + quad * 4;
#pragma unroll
      for (int j = 0; j < 4; j++) {
        int col = colBase + wcol * 64 + j * 16 + lane15;
#pragma unroll
        for (int rr = 0; rr < 4; rr++)
          Cb[(size_t)(row + rr) * N + col] = f2b(acc[i][j][rr]);
      }
    }
  }
}

// ---------------------------------------------------------------------------
// RoPE in-place on bf16 Q [M, 2048] and K [M, 512]; cos/sin f32.
// ---------------------------------------------------------------------------
__global__ void rope_k(unsigned short* __restrict__ Qb, unsigned short* __restrict__ Kb,
                       const float* __restrict__ cosT, const float* __restrict__ sinT)
{
  const int per_tok = (NH_ + NKV_) * 64;
  int idx = blockIdx.x * blockDim.x + threadIdx.x;
  int t = idx / per_tok;
  int r = idx - t * per_tok;
  if (t >= M_) return;
  int s = t & (S_ - 1);
  unsigned short* base;
  int d;
  if (r < NH_ * 64) {
    int h = r >> 6; d = r & 63;
    base = Qb + (size_t)t * (NH_ * HD_) + h * HD_ + d;
  } else {
    int rk = r - NH_ * 64;
    int h = rk >> 6; d = rk & 63;
    base = Kb + (size_t)t * (NKV_ * HD_) + h * HD_ + d;
  }
  float c  = cosT[s * HD_ + d];
  float sn = sinT[s * HD_ + d];
  float x0 = b2f(base[0]);
  float x1 = b2f(base[64]);
  base[0]  = f2b(x0 * c - x1 * sn);
  base[64] = f2b(x1 * c + x0 * sn);
}

// ---------------------------------------------------------------------------
// V transpose: Vb[M,512] -> VT[B*512, 2048] (dim-major). 64x64 LDS tiles.
// ---------------------------------------------------------------------------
__global__ void transp_v(const unsigned short* __restrict__ Vb, unsigned short* __restrict__ VT)
{
  __shared__ unsigned short Ls[64 * 72];
  const int t0 = blockIdx.x * 64;
  const int d0 = blockIdx.y * 64;
  const int tid = threadIdx.x;
  const int r = tid >> 3, c = tid & 7;
#pragma unroll
  for (int p = 0; p < 2; p++)
    *reinterpret_cast<uint4*>(Ls + (r + 32 * p) * 72 + c * 8) =
      *reinterpret_cast<const uint4*>(Vb + (size_t)(t0 + r + 32 * p) * (NKV_ * HD_) + d0 + c * 8);
  __syncthreads();
  const int bq = t0 >> 11, s0 = t0 & (S_ - 1);
#pragma unroll
  for (int p = 0; p < 2; p++) {
    int dl = r + 32 * p;
    unsigned short tmp[8];
#pragma unroll
    for (int j = 0; j < 8; j++) tmp[j] = Ls[(c * 8 + j) * 72 + dl];
    *reinterpret_cast<uint4*>(VT + (size_t)(bq * 512 + d0 + dl) * S_ + s0 + c * 8) =
      *reinterpret_cast<uint4*>(tmp);
  }
}

// ---------------------------------------------------------------------------
// Flash attention v6: v5's 32x32x16 swapped-QK + in-register softmax (T12),
// re-partitioned into 4-wave 256-thread blocks: block = (b, kvh, 32-row
// q-group g in 0..63) x 4 heads. Grid = 512 blocks -> 2 blocks/CU GUARANTEED
// co-resident (LDS 2x33KB, 8 waves, VGPR ~124) = two independent barrier
// domains per CU; one block's MFMA/exp overlaps the other's staging/barrier.
// g = b ? 63-x : x so CU-paired blocks have complementary causal depth.
// T5 setprio around MFMA clusters (arbitration across co-resident blocks).
// ---------------------------------------------------------------------------
__global__ __launch_bounds__(256, 2) void attn(
    const unsigned short* __restrict__ Q, const unsigned short* __restrict__ Kc,
    const unsigned short* __restrict__ VT, unsigned short* __restrict__ O)
{
  __shared__ unsigned short Ks[64 * 128];   // [key][hd], chunk16B ^= (key&15)
  __shared__ unsigned short Vs[128 * 64];   // [dim][key], chunk16B ^= (dim&7)
  __shared__ float Ll[4 * 32];              // per-wave 1/l broadcast

  const int tid  = threadIdx.x;
  const int lane = tid & 63;
  const int w    = tid >> 6;              // 0..3 = head within kv group
  const int l31  = lane & 31;
  const int hi   = lane >> 5;
  const int x    = blockIdx.x;            // 0..63
  const int kvh  = blockIdx.y;
  const int b    = blockIdx.z;
  const int g    = b ? (63 - x) : x;      // 32-row q-group; complementary across b
  const int h    = kvh * 4 + w;
  const size_t bS = (size_t)b * S_;
  const int nkt  = g / 2 + 1;             // key tiles of 64 covering keys <= g*32+31

  // staging thread mapping (256 threads, 4 rounds)
  const int kr   = tid >> 4;      // K row 0..15 (+16 per round)
  const int kc16 = tid & 15;      // K 16B-chunk 0..15
  const int vd   = tid >> 3;      // V dim 0..31 (+32 per round)
  const int vc8  = tid & 7;       // V 16B-chunk 0..7

  const unsigned short* Kbase = Kc + bS * (NKV_ * HD_) + kvh * HD_;
  const unsigned short* Vbase = VT + (size_t)(b * 512 + kvh * HD_) * S_;

  // Q fragments (B-operand of swapped QK): lane holds Q[q = g*32+l31][k = kc*16 + hi*8 + j]
  bf16x8 qf[8];
  {
    const unsigned short* qp = Q + (bS + g * 32 + l31) * (NH_ * HD_) + h * HD_ + hi * 8;
#pragma unroll
    for (int kc = 0; kc < 8; kc++) qf[kc] = *reinterpret_cast<const bf16x8*>(qp + kc * 16);
  }

  f32x16 ctx[4];
#pragma unroll
  for (int ng = 0; ng < 4; ng++)
#pragma unroll
    for (int r = 0; r < 16; r++) ctx[ng][r] = 0.f;
  float lsum = 0.f;

  // prefetch tile 0
  uint4 kreg[4], vreg[4];
#pragma unroll
  for (int p2 = 0; p2 < 4; p2++) {
    kreg[p2] = *reinterpret_cast<const uint4*>(Kbase + (size_t)(kr + 16 * p2) * (NKV_ * HD_) + kc16 * 8);
    vreg[p2] = *reinterpret_cast<const uint4*>(Vbase + (size_t)(vd + 32 * p2) * S_ + vc8 * 8);
  }

  const float scale = 0.08838834764831845f;

  for (int kt = 0; kt < nkt; kt++) {
    __syncthreads();
#pragma unroll
    for (int p2 = 0; p2 < 4; p2++) {
      const int row = kr + 16 * p2;
      *reinterpret_cast<uint4*>(Ks + row * 128 + ((kc16 ^ (row & 15)) * 8)) = kreg[p2];
      const int d = vd + 32 * p2;
      *reinterpret_cast<uint4*>(Vs + d * 64 + ((vc8 ^ (d & 7)) * 8)) = vreg[p2];
    }
    __syncthreads();

    if (kt + 1 < nkt) {
      const int key0 = (kt + 1) * 64;
#pragma unroll
      for (int p2 = 0; p2 < 4; p2++) {
        kreg[p2] = *reinterpret_cast<const uint4*>(Kbase + (size_t)(key0 + kr + 16 * p2) * (NKV_ * HD_) + kc16 * 8);
        vreg[p2] = *reinterpret_cast<const uint4*>(Vbase + (size_t)(vd + 32 * p2) * S_ + key0 + vc8 * 8);
      }
    }

    // swapped QK^T: sc = D[key_local][q = l31]
    f32x16 sc0, sc1;
#pragma unroll
    for (int r = 0; r < 16; r++) { sc0[r] = 0.f; sc1[r] = 0.f; }
    __builtin_amdgcn_s_setprio(1);
#pragma unroll
    for (int kc = 0; kc < 8; kc++) {
      const int ch = ((kc * 2 + hi) ^ (l31 & 15)) * 8;
      bf16x8 kf0 = *reinterpret_cast<const bf16x8*>(Ks + l31 * 128 + ch);
      sc0 = __builtin_amdgcn_mfma_f32_32x32x16_bf16(kf0, qf[kc], sc0, 0, 0, 0);
      bf16x8 kf1 = *reinterpret_cast<const bf16x8*>(Ks + (32 + l31) * 128 + ch);
      sc1 = __builtin_amdgcn_mfma_f32_32x32x16_bf16(kf1, qf[kc], sc1, 0, 0, 0);
    }
    __builtin_amdgcn_s_setprio(0);

    // scale + causal mask (last tile only) + exp + pack to bf16 A-fragments
    // q-row (global) = g*32 + l31; key (global) = kt*64 + kp.
    const int lim = (kt == nkt - 1) ? (g * 32 + l31 - kt * 64) : 4096;
    bf16x8 pfrag[4];
#pragma unroll
    for (int cg = 0; cg < 2; cg++) {
      float pe[16];
#pragma unroll
      for (int r = 0; r < 16; r++) {
        float v = (cg ? sc1[r] : sc0[r]) * scale;
        const int kp = cg * 32 + (r & 3) + 8 * (r >> 2) + 4 * hi;  // key_local
        v = (kp <= lim) ? v : -1.0e9f;
        float e = __expf(v);
        pe[r] = e;
        lsum += e;
      }
      unsigned wd[8];
#pragma unroll
      for (int j = 0; j < 8; j++) {
        unsigned t;
        asm("v_cvt_pk_bf16_f32 %0, %1, %2" : "=v"(t) : "v"(pe[2 * j]), "v"(pe[2 * j + 1]));
        wd[j] = t;
      }
      asm("v_permlane32_swap_b32 %0, %1" : "+v"(wd[0]), "+v"(wd[2]));
      asm("v_permlane32_swap_b32 %0, %1" : "+v"(wd[1]), "+v"(wd[3]));
      asm("v_permlane32_swap_b32 %0, %1" : "+v"(wd[4]), "+v"(wd[6]));
      asm("v_permlane32_swap_b32 %0, %1" : "+v"(wd[5]), "+v"(wd[7]));
      union { unsigned u[4]; bf16x8 v8; } ua, ub;
      ua.u[0] = wd[0]; ua.u[1] = wd[1]; ua.u[2] = wd[2]; ua.u[3] = wd[3];
      ub.u[0] = wd[4]; ub.u[1] = wd[5]; ub.u[2] = wd[6]; ub.u[3] = wd[7];
      pfrag[cg * 2]     = ua.v8;   // keys cg*32 + 0..15
      pfrag[cg * 2 + 1] = ub.v8;   // keys cg*32 + 16..31
    }

    // PV: ctx[ng] += P[q][key] * V[key][d],  d = ng*32 + l31
    __builtin_amdgcn_s_setprio(1);
#pragma unroll
    for (int ng = 0; ng < 4; ng++) {
      const int drow = ng * 32 + l31;
#pragma unroll
      for (int kc = 0; kc < 4; kc++) {
        bf16x8 vf = *reinterpret_cast<const bf16x8*>(Vs + drow * 64 + (((kc * 2 + hi) ^ (l31 & 7)) * 8));
        ctx[ng] = __builtin_amdgcn_mfma_f32_32x32x16_bf16(pfrag[kc], vf, ctx[ng], 0, 0, 0);
      }
    }
    __builtin_amdgcn_s_setprio(0);
  }

  // epilogue: combine l across hi halves, broadcast 1/l via per-wave LDS
  {
    float lt = lsum + __shfl_xor(lsum, 32);
    Ll[w * 32 + l31] = 1.0f / lt;
  }
  __syncthreads();
  f32x4 iv[4];
#pragma unroll
  for (int g4 = 0; g4 < 4; g4++)
    iv[g4] = *reinterpret_cast<const f32x4*>(&Ll[w * 32 + 4 * hi + 8 * g4]);

  const size_t orow0 = bS + g * 32;
#pragma unroll
  for (int ng = 0; ng < 4; ng++) {
#pragma unroll
    for (int r = 0; r < 16; r++) {
      const int qp = (r & 3) + 8 * (r >> 2) + 4 * hi;
      O[(orow0 + qp) * (NH_ * HD_) + h * HD_ + ng * 32 + l31] = f2b(ctx[ng][r] * iv[r >> 2][r & 3]);
    }
  }
}

// ---------------------------------------------------------------------------
// Launcher. Big path (ws >= ~54.5 MB): pre-convert x + weights to bf16 in ws,
// all GEMMs via gemm_ld (global_load_lds). Fallback: exact round-8 pipeline.
// d_out head holds Kb/Vb/VT (12 MB), consumed before final GEMM overwrites out.
// ---------------------------------------------------------------------------
extern "C" void kernel_launch(void* const* d_in, const int* in_sizes, int n_in,
                              void* d_out, int out_size, void* d_ws, size_t ws_size,
                              hipStream_t stream) {
  const float* x    = (const float*)d_in[0];
  const float* Wq   = (const float*)d_in[1];
  const float* Wk   = (const float*)d_in[2];
  const float* Wv   = (const float*)d_in[3];
  const float* Wo   = (const float*)d_in[4];
  const float* cosT = (const float*)d_in[5];
  const float* sinT = (const float*)d_in[6];
  float* out = (float*)d_out;

  const size_t qElems  = (size_t)M_ * NH_ * HD_;   // 8.39 M
  const size_t xElems  = (size_t)M_ * H_;          // 8.39 M
  const size_t wqElems = (size_t)H_ * H_;          // 4.19 M
  const size_t wkElems = (size_t)NKV_ * HD_ * H_;  // 1.05 M
  const size_t bigNeed = (qElems + xElems + 2 * wqElems + 2 * wkElems) * 2 + 256;

  if (ws_size < qElems * 2 + 256) return;

  unsigned short* Qb = (unsigned short*)d_ws;
  unsigned short* Kb = (unsigned short*)d_out;
  unsigned short* Vb = Kb + (size_t)M_ * NKV_ * HD_;
  unsigned short* VT = Vb + (size_t)M_ * NKV_ * HD_;

  dim3 blk(256);
  const int rope_threads = M_ * (NH_ + NKV_) * 64;

  if (ws_size >= bigNeed) {
    unsigned short* xb  = Qb + qElems;
    unsigned short* Wqb = xb + xElems;
    unsigned short* Wob = Wqb + wqElems;
    unsigned short* Wkb = Wob + wqElems;
    unsigned short* Wvb = Wkb + wkElems;

    cvt_bf16<<<dim3((int)(xElems / 8 + 255) / 256), blk, 0, stream>>>(x,  xb,  (int)(xElems / 8));
    cvt_bf16<<<dim3((int)(wqElems / 8 + 255) / 256), blk, 0, stream>>>(Wq, Wqb, (int)(wqElems / 8));
    cvt_bf16<<<dim3((int)(wkElems / 8 + 255) / 256), blk, 0, stream>>>(Wk, Wkb, (int)(wkElems / 8));
    cvt_bf16<<<dim3((int)(wkElems / 8 + 255) / 256), blk, 0, stream>>>(Wv, Wvb, (int)(wkElems / 8));
    cvt_bf16<<<dim3((int)(wqElems / 8 + 255) / 256), blk, 0, stream>>>(Wo, Wob, (int)(wqElems / 8));

    gemm_ld<false><<<dim3(16, 32), blk, 0, stream>>>(xb, Wqb, Wqb, Qb, Qb, NH_ * HD_, H_, 16);
    gemm_ld<false><<<dim3(8, 32), blk, 0, stream>>>(xb, Wkb, Wvb, Kb, Vb, NKV_ * HD_, H_, 4);

    rope_k<<<dim3((rope_threads + 255) / 256), blk, 0, stream>>>(Qb, Kb, cosT, sinT);
    transp_v<<<dim3(M_ / 64, (NKV_ * HD_) / 64), blk, 0, stream>>>(Vb, VT);
    attn<<<dim3(64, NKV_, B_), dim3(256), 0, stream>>>(Qb, Kb, VT, Qb);

    gemm_ld<true><<<dim3(16, 32), blk, 0, stream>>>(Qb, Wob, Wob, out, out, H_, NH_ * HD_, 16);
  } else {
    gemm_k<false><<<dim3(16, 32), blk, 0, stream>>>(x, Wq, Wq, Qb, Qb, NH_ * HD_, H_, 16);
    gemm_k<false><<<dim3(8, 32), blk, 0, stream>>>(x, Wk, Wv, Kb, Vb, NKV_ * HD_, H_, 4);

    rope_k<<<dim3((rope_threads + 255) / 256), blk, 0, stream>>>(Qb, Kb, cosT, sinT);
    transp_v<<<dim3(M_ / 64, (NKV_ * HD_) / 64), blk, 0, stream>>>(Vb, VT);
    attn<<<dim3(64, NKV_, B_), dim3(256), 0, stream>>>(Qb, Kb, VT, Qb);

    gemm_k<true><<<dim3(16, 32), blk, 0, stream>>>(Qb, Wo, Wo, out, out, H_, NH_ * HD_, 16);
  }
}

// Round 5
// 364.725 us; speedup vs baseline: 1.1981x; 1.1981x over previous
//
#include <hip/hip_runtime.h>
#include <stdint.h>

#define B_   2
#define S_   2048
#define H_   2048
#define NH_  16
#define NKV_ 4
#define HD_  128
#define M_   (B_ * S_)   // 4096

typedef short bf16x8 __attribute__((ext_vector_type(8)));
typedef float f32x4  __attribute__((ext_vector_type(4)));
typedef float f32x16 __attribute__((ext_vector_type(16)));

__device__ __forceinline__ float b2f(unsigned short u) {
  union { unsigned int u; float f; } v; v.u = ((unsigned int)u) << 16; return v.f;
}
__device__ __forceinline__ unsigned short f2b(float f) {
  union { float f; unsigned int u; } v; v.f = f;
  unsigned int u = v.u;
  unsigned int r = (u + 0x7FFFu + ((u >> 16) & 1u)) >> 16;
  return (unsigned short)r;
}
__device__ __forceinline__ uint4 pack8(const float4& a, const float4& b) {
  uint4 r;
  r.x = (unsigned)f2b(a.x) | ((unsigned)f2b(a.y) << 16);
  r.y = (unsigned)f2b(a.z) | ((unsigned)f2b(a.w) << 16);
  r.z = (unsigned)f2b(b.x) | ((unsigned)f2b(b.y) << 16);
  r.w = (unsigned)f2b(b.z) | ((unsigned)f2b(b.w) << 16);
  return r;
}
// async global -> LDS, 16 B per lane; dest = lds base (wave-uniform) + lane*16
__device__ __forceinline__ void gload_lds(const unsigned short* g, unsigned short* l) {
  __builtin_amdgcn_global_load_lds(
      (const __attribute__((address_space(1))) unsigned int*)g,
      (__attribute__((address_space(3))) unsigned int*)l, 16, 0, 0);
}

// ---------------------------------------------------------------------------
// f32 -> bf16 bulk convert (8 elems/thread, coalesced 16B stores)
// ---------------------------------------------------------------------------
__global__ void cvt_bf16(const float* __restrict__ src, unsigned short* __restrict__ dst, int n8)
{
  int i = blockIdx.x * blockDim.x + threadIdx.x;
  if (i >= n8) return;
  const float* p = src + (size_t)i * 8;
  uint4 v = pack8(*reinterpret_cast<const float4*>(p), *reinterpret_cast<const float4*>(p + 4));
  *reinterpret_cast<uint4*>(dst + (size_t)i * 8) = v;
}

// ---------------------------------------------------------------------------
// gemm_ld: C[M,N] = A[M,K] @ B[N,K]^T, all-bf16 inputs, f32 acc.
// m97-style: 128x128 tile, BK=64, global_load_lds width=16 staging,
// XOR-swizzled LDS (chunk ^= row&7) so ds_read_b128 fragments are 2-way/bank.
// Dual-output: blockIdx.x < nxHalf -> (B0,C0) else (B1,C1). CF32: f32 C.
// ---------------------------------------------------------------------------
template<bool CF32>
__global__ __launch_bounds__(256, 4) void gemm_ld(
    const unsigned short* __restrict__ A, const unsigned short* __restrict__ B0,
    const unsigned short* __restrict__ B1, void* __restrict__ C0, void* __restrict__ C1,
    int N, int K, int nxHalf)
{
  __shared__ unsigned short As[128 * 64];   // unpadded (DMA dest must be contiguous)
  __shared__ unsigned short Bs[128 * 64];

  const unsigned short* Bm; void* Cm; int colBase;
  if ((int)blockIdx.x < nxHalf) { Bm = B0; Cm = C0; colBase = blockIdx.x * 128; }
  else                          { Bm = B1; Cm = C1; colBase = (blockIdx.x - nxHalf) * 128; }
  const int rowBase = blockIdx.y * 128;

  const int tid    = threadIdx.x;
  const int lane   = tid & 63;
  const int wid    = tid >> 6;
  const int wrow   = wid >> 1;
  const int wcol   = wid & 1;
  const int lane15 = lane & 15;
  const int quad   = lane >> 4;

  const f32x4 zero = {0.f, 0.f, 0.f, 0.f};
  f32x4 acc[4][4];
#pragma unroll
  for (int i = 0; i < 4; i++)
#pragma unroll
    for (int j = 0; j < 4; j++) acc[i][j] = zero;

  const int lr  = lane >> 3;
  const int sc8 = (lane & 7) ^ lr;      // source chunk for this lane (all issues)

  for (int kb = 0; kb < K; kb += 64) {
    __syncthreads();                    // previous compute done reading LDS
#pragma unroll
    for (int i = 0; i < 4; i++) {
      const int rg = (i * 4 + wid) * 8;
      const int r  = rg + lr;
      gload_lds(A  + (size_t)(rowBase + r) * K + kb + sc8 * 8, As + rg * 64);
      gload_lds(Bm + (size_t)(colBase + r) * K + kb + sc8 * 8, Bs + rg * 64);
    }
    __syncthreads();                    // compiler drains vmcnt(0) before barrier
#pragma unroll
    for (int kc = 0; kc < 2; kc++) {
      bf16x8 af[4], bf[4];
#pragma unroll
      for (int g = 0; g < 4; g++) {
        const int ra = wrow * 64 + g * 16 + lane15;
        const int rb = wcol * 64 + g * 16 + lane15;
        af[g] = *reinterpret_cast<const bf16x8*>(As + ra * 64 + (((kc * 4 + quad) ^ (ra & 7)) * 8));
        bf[g] = *reinterpret_cast<const bf16x8*>(Bs + rb * 64 + (((kc * 4 + quad) ^ (rb & 7)) * 8));
      }
#pragma unroll
      for (int i = 0; i < 4; i++)
#pragma unroll
        for (int j = 0; j < 4; j++)
          acc[i][j] = __builtin_amdgcn_mfma_f32_16x16x32_bf16(af[i], bf[j], acc[i][j], 0, 0, 0);
    }
  }

  if (CF32) {
    float* Cf = (float*)Cm;
#pragma unroll
    for (int i = 0; i < 4; i++) {
      int row = rowBase + wrow * 64 + i * 16 + quad * 4;
#pragma unroll
      for (int j = 0; j < 4; j++) {
        int col = colBase + wcol * 64 + j * 16 + lane15;
#pragma unroll
        for (int rr = 0; rr < 4; rr++)
          Cf[(size_t)(row + rr) * N + col] = acc[i][j][rr];
      }
    }
  } else {
    unsigned short* Cb = (unsigned short*)Cm;
#pragma unroll
    for (int i = 0; i < 4; i++) {
      int row = rowBase + wrow * 64 + i * 16 + quad * 4;
#pragma unroll
      for (int j = 0; j < 4; j++) {
        int col = colBase + wcol * 64 + j * 16 + lane15;
#pragma unroll
        for (int rr = 0; rr < 4; rr++)
          Cb[(size_t)(row + rr) * N + col] = f2b(acc[i][j][rr]);
      }
    }
  }
}

// ---------------------------------------------------------------------------
// Fallback GEMM (round-8 proven): VGPR-roundtrip staging, f32 B packed at load.
// ---------------------------------------------------------------------------
template<bool OPROJ>
__global__ __launch_bounds__(256, 3) void gemm_k(
    const void* __restrict__ A, const float* __restrict__ B0, const float* __restrict__ B1,
    void* __restrict__ C0, void* __restrict__ C1, int N, int K, int nxHalf)
{
  __shared__ unsigned short As[128 * 72];
  __shared__ unsigned short Bs[128 * 72];

  const float* Bm; void* Cm; int colBase;
  if ((int)blockIdx.x < nxHalf) { Bm = B0; Cm = C0; colBase = blockIdx.x * 128; }
  else                          { Bm = B1; Cm = C1; colBase = (blockIdx.x - nxHalf) * 128; }
  const int rowBase = blockIdx.y * 128;

  const int tid    = threadIdx.x;
  const int lane   = tid & 63;
  const int wid    = tid >> 6;
  const int wrow   = wid >> 1;
  const int wcol   = wid & 1;
  const int lane15 = lane & 15;
  const int quad   = lane >> 4;

  const f32x4 zero = {0.f, 0.f, 0.f, 0.f};
  f32x4 acc[4][4];
#pragma unroll
  for (int i = 0; i < 4; i++)
#pragma unroll
    for (int j = 0; j < 4; j++) acc[i][j] = zero;

  const int r0 = tid >> 3;
  const int c8 = tid & 7;

  uint4 av[4], bv[4];
#pragma unroll
  for (int p = 0; p < 4; p++) {
    int r = r0 + 32 * p;
    if (OPROJ) {
      av[p] = *reinterpret_cast<const uint4*>((const unsigned short*)A + (size_t)(rowBase + r) * K + c8 * 8);
    } else {
      const float* pA = (const float*)A + (size_t)(rowBase + r) * K + c8 * 8;
      av[p] = pack8(*reinterpret_cast<const float4*>(pA), *reinterpret_cast<const float4*>(pA + 4));
    }
    const float* pB = Bm + (size_t)(colBase + r) * K + c8 * 8;
    bv[p] = pack8(*reinterpret_cast<const float4*>(pB), *reinterpret_cast<const float4*>(pB + 4));
  }

  for (int kb = 0; kb < K; kb += 64) {
    __syncthreads();
#pragma unroll
    for (int p = 0; p < 4; p++) {
      int r = r0 + 32 * p;
      *reinterpret_cast<uint4*>(As + r * 72 + c8 * 8) = av[p];
      *reinterpret_cast<uint4*>(Bs + r * 72 + c8 * 8) = bv[p];
    }
    __syncthreads();
    const int kn = kb + 64;
    if (kn < K) {
#pragma unroll
      for (int p = 0; p < 4; p++) {
        int r = r0 + 32 * p;
        if (OPROJ) {
          av[p] = *reinterpret_cast<const uint4*>((const unsigned short*)A + (size_t)(rowBase + r) * K + kn + c8 * 8);
        } else {
          const float* pA = (const float*)A + (size_t)(rowBase + r) * K + kn + c8 * 8;
          av[p] = pack8(*reinterpret_cast<const float4*>(pA), *reinterpret_cast<const float4*>(pA + 4));
        }
        const float* pB = Bm + (size_t)(colBase + r) * K + kn + c8 * 8;
        bv[p] = pack8(*reinterpret_cast<const float4*>(pB), *reinterpret_cast<const float4*>(pB + 4));
      }
    }
#pragma unroll
    for (int kc = 0; kc < 2; kc++) {
      bf16x8 af[4], bf[4];
#pragma unroll
      for (int g = 0; g < 4; g++) {
        af[g] = *reinterpret_cast<const bf16x8*>(As + (wrow * 64 + g * 16 + lane15) * 72 + kc * 32 + quad * 8);
        bf[g] = *reinterpret_cast<const bf16x8*>(Bs + (wcol * 64 + g * 16 + lane15) * 72 + kc * 32 + quad * 8);
      }
#pragma unroll
      for (int i = 0; i < 4; i++)
#pragma unroll
        for (int j = 0; j < 4; j++)
          acc[i][j] = __builtin_amdgcn_mfma_f32_16x16x32_bf16(af[i], bf[j], acc[i][j], 0, 0, 0);
    }
  }

  if (OPROJ) {
    float* Cf = (float*)Cm;
#pragma unroll
    for (int i = 0; i < 4; i++) {
      int row = rowBase + wrow * 64 + i * 16 + quad * 4;
#pragma unroll
      for (int j = 0; j < 4; j++) {
        int col = colBase + wcol * 64 + j * 16 + lane15;
#pragma unroll
        for (int rr = 0; rr < 4; rr++)
          Cf[(size_t)(row + rr) * N + col] = acc[i][j][rr];
      }
    }
  } else {
    unsigned short* Cb = (unsigned short*)Cm;
#pragma unroll
    for (int i = 0; i < 4; i++) {
      int row = rowBase + wrow * 64 + i * 16 + quad * 4;
#pragma unroll
      for (int j = 0; j < 4; j++) {
        int col = colBase + wcol * 64 + j * 16 + lane15;
#pragma unroll
        for (int rr = 0; rr < 4; rr++)
          Cb[(size_t)(row + rr) * N + col] = f2b(acc[i][j][rr]);
      }
    }
  }
}

// ---------------------------------------------------------------------------
// RoPE in-place on bf16 Q [M, 2048] and K [M, 512]; cos/sin f32.
// ---------------------------------------------------------------------------
__global__ void rope_k(unsigned short* __restrict__ Qb, unsigned short* __restrict__ Kb,
                       const float* __restrict__ cosT, const float* __restrict__ sinT)
{
  const int per_tok = (NH_ + NKV_) * 64;
  int idx = blockIdx.x * blockDim.x + threadIdx.x;
  int t = idx / per_tok;
  int r = idx - t * per_tok;
  if (t >= M_) return;
  int s = t & (S_ - 1);
  unsigned short* base;
  int d;
  if (r < NH_ * 64) {
    int h = r >> 6; d = r & 63;
    base = Qb + (size_t)t * (NH_ * HD_) + h * HD_ + d;
  } else {
    int rk = r - NH_ * 64;
    int h = rk >> 6; d = rk & 63;
    base = Kb + (size_t)t * (NKV_ * HD_) + h * HD_ + d;
  }
  float c  = cosT[s * HD_ + d];
  float sn = sinT[s * HD_ + d];
  float x0 = b2f(base[0]);
  float x1 = b2f(base[64]);
  base[0]  = f2b(x0 * c - x1 * sn);
  base[64] = f2b(x1 * c + x0 * sn);
}

// ---------------------------------------------------------------------------
// V transpose: Vb[M,512] -> VT[B*512, 2048] (dim-major). 64x64 LDS tiles.
// ---------------------------------------------------------------------------
__global__ void transp_v(const unsigned short* __restrict__ Vb, unsigned short* __restrict__ VT)
{
  __shared__ unsigned short Ls[64 * 72];
  const int t0 = blockIdx.x * 64;
  const int d0 = blockIdx.y * 64;
  const int tid = threadIdx.x;
  const int r = tid >> 3, c = tid & 7;
#pragma unroll
  for (int p = 0; p < 2; p++)
    *reinterpret_cast<uint4*>(Ls + (r + 32 * p) * 72 + c * 8) =
      *reinterpret_cast<const uint4*>(Vb + (size_t)(t0 + r + 32 * p) * (NKV_ * HD_) + d0 + c * 8);
  __syncthreads();
  const int bq = t0 >> 11, s0 = t0 & (S_ - 1);
#pragma unroll
  for (int p = 0; p < 2; p++) {
    int dl = r + 32 * p;
    unsigned short tmp[8];
#pragma unroll
    for (int j = 0; j < 8; j++) tmp[j] = Ls[(c * 8 + j) * 72 + dl];
    *reinterpret_cast<uint4*>(VT + (size_t)(bq * 512 + d0 + dl) * S_ + s0 + c * 8) =
      *reinterpret_cast<uint4*>(tmp);
  }
}

// ---------------------------------------------------------------------------
// Flash attention v8: v5's verified 32x32x16 swapped-QK + in-register softmax
// (T12) + v7's double-buffered K/V LDS (ONE barrier per iteration; stage-write
// targets the buffer not being read). Pairing DROPPED (v7's duplicated-tile
// bug): one q-tile per block, g = blockIdx.x, nkt = g+1 -> trivially safe
// with O aliasing Q (block g is the only reader AND only writer of tile g,
// and reads happen before its own write). Imbalance costs ~5% (v5 evidence).
// LDS = 2x(16+16) KB = 64 KB; 1/l broadcast via shuffles (no LDS).
// Grid (32, NKV, B) = 256 blocks x 512 thr (8 waves = 4 heads x 2 rowgroups).
// ---------------------------------------------------------------------------
__global__ __launch_bounds__(512, 1) void attn(
    const unsigned short* __restrict__ Q, const unsigned short* __restrict__ Kc,
    const unsigned short* __restrict__ VT, unsigned short* __restrict__ O)
{
  __shared__ unsigned short KsA[2 * 64 * 128];   // [buf][key][hd], chunk16B ^= (key&15)
  __shared__ unsigned short VsA[2 * 128 * 64];   // [buf][dim][key], chunk16B ^= (dim&7)

  const int tid  = threadIdx.x;
  const int lane = tid & 63;
  const int w    = tid >> 6;
  const int l31  = lane & 31;
  const int hi   = lane >> 5;
  const int g    = blockIdx.x;            // q-tile 0..31
  const int kvh  = blockIdx.y;
  const int b    = blockIdx.z;
  const int h    = kvh * 4 + (w & 3);
  const int rg   = w >> 2;                // 0..1: rows rg*32..rg*32+31
  const size_t bS = (size_t)b * S_;
  const int nkt  = g + 1;
  const int qb   = g * 64;

  // staging thread mapping (512 threads)
  const int kr   = tid >> 4;      // K row 0..31 (+32 per round)
  const int kc16 = tid & 15;      // K 16B-chunk 0..15
  const int vd   = tid >> 3;      // V dim 0..63 (+64 per round)
  const int vc8  = tid & 7;       // V 16B-chunk 0..7

  const unsigned short* Kbase = Kc + bS * (NKV_ * HD_) + kvh * HD_;
  const unsigned short* Vbase = VT + (size_t)(b * 512 + kvh * HD_) * S_;

  // Q fragments (B-operand of swapped QK): lane holds Q[q = qb+rg*32+l31][k = kc*16 + hi*8 + j]
  bf16x8 qf[8];
  {
    const unsigned short* qp = Q + (bS + qb + rg * 32 + l31) * (NH_ * HD_) + h * HD_ + hi * 8;
#pragma unroll
    for (int kc = 0; kc < 8; kc++) qf[kc] = *reinterpret_cast<const bf16x8*>(qp + kc * 16);
  }

  f32x16 ctx[4];
#pragma unroll
  for (int ng = 0; ng < 4; ng++)
#pragma unroll
    for (int r = 0; r < 16; r++) ctx[ng][r] = 0.f;
  float lsum = 0.f;

  const float scale = 0.08838834764831845f;

  // prologue: tile 0 -> buf 0
  uint4 kreg[2], vreg[2];
#pragma unroll
  for (int p2 = 0; p2 < 2; p2++) {
    kreg[p2] = *reinterpret_cast<const uint4*>(Kbase + (size_t)(kr + 32 * p2) * (NKV_ * HD_) + kc16 * 8);
    vreg[p2] = *reinterpret_cast<const uint4*>(Vbase + (size_t)(vd + 64 * p2) * S_ + vc8 * 8);
  }
#pragma unroll
  for (int p2 = 0; p2 < 2; p2++) {
    const int row = kr + 32 * p2;
    *reinterpret_cast<uint4*>(KsA + row * 128 + ((kc16 ^ (row & 15)) * 8)) = kreg[p2];
    const int d = vd + 64 * p2;
    *reinterpret_cast<uint4*>(VsA + d * 64 + ((vc8 ^ (d & 7)) * 8)) = vreg[p2];
  }
  __syncthreads();

  for (int kt = 0; kt < nkt; kt++) {
    unsigned short* ksc = KsA + (kt & 1) * 8192;
    unsigned short* vsc = VsA + (kt & 1) * 8192;
    unsigned short* ksn = KsA + ((kt & 1) ^ 1) * 8192;
    unsigned short* vsn = VsA + ((kt & 1) ^ 1) * 8192;

    // issue next tile's global loads (latency hides under this tile's compute)
    if (kt + 1 < nkt) {
      const int key0 = (kt + 1) * 64;
#pragma unroll
      for (int p2 = 0; p2 < 2; p2++) {
        kreg[p2] = *reinterpret_cast<const uint4*>(Kbase + (size_t)(key0 + kr + 32 * p2) * (NKV_ * HD_) + kc16 * 8);
        vreg[p2] = *reinterpret_cast<const uint4*>(Vbase + (size_t)(vd + 64 * p2) * S_ + key0 + vc8 * 8);
      }
    }

    // swapped QK^T: sc = D[key_local][q = l31]
    f32x16 sc0, sc1;
#pragma unroll
    for (int r = 0; r < 16; r++) { sc0[r] = 0.f; sc1[r] = 0.f; }
    __builtin_amdgcn_s_setprio(1);
#pragma unroll
    for (int kc = 0; kc < 8; kc++) {
      const int ch = ((kc * 2 + hi) ^ (l31 & 15)) * 8;
      bf16x8 kf0 = *reinterpret_cast<const bf16x8*>(ksc + l31 * 128 + ch);
      sc0 = __builtin_amdgcn_mfma_f32_32x32x16_bf16(kf0, qf[kc], sc0, 0, 0, 0);
      bf16x8 kf1 = *reinterpret_cast<const bf16x8*>(ksc + (32 + l31) * 128 + ch);
      sc1 = __builtin_amdgcn_mfma_f32_32x32x16_bf16(kf1, qf[kc], sc1, 0, 0, 0);
    }
    __builtin_amdgcn_s_setprio(0);

    // scale + causal mask (last tile only: kt*64 == qb) + exp + pack
    const int lim = (kt == nkt - 1) ? (rg * 32 + l31) : 4096;
    bf16x8 pfrag[4];
#pragma unroll
    for (int cg = 0; cg < 2; cg++) {
      float pe[16];
#pragma unroll
      for (int r = 0; r < 16; r++) {
        float v = (cg ? sc1[r] : sc0[r]) * scale;
        const int kp = cg * 32 + (r & 3) + 8 * (r >> 2) + 4 * hi;  // key_local
        v = (kp <= lim) ? v : -1.0e9f;
        float e = __expf(v);
        pe[r] = e;
        lsum += e;
      }
      unsigned wd[8];
#pragma unroll
      for (int j = 0; j < 8; j++) {
        unsigned t;
        asm("v_cvt_pk_bf16_f32 %0, %1, %2" : "=v"(t) : "v"(pe[2 * j]), "v"(pe[2 * j + 1]));
        wd[j] = t;
      }
      asm("v_permlane32_swap_b32 %0, %1" : "+v"(wd[0]), "+v"(wd[2]));
      asm("v_permlane32_swap_b32 %0, %1" : "+v"(wd[1]), "+v"(wd[3]));
      asm("v_permlane32_swap_b32 %0, %1" : "+v"(wd[4]), "+v"(wd[6]));
      asm("v_permlane32_swap_b32 %0, %1" : "+v"(wd[5]), "+v"(wd[7]));
      union { unsigned u[4]; bf16x8 v8; } ua, ub;
      ua.u[0] = wd[0]; ua.u[1] = wd[1]; ua.u[2] = wd[2]; ua.u[3] = wd[3];
      ub.u[0] = wd[4]; ub.u[1] = wd[5]; ub.u[2] = wd[6]; ub.u[3] = wd[7];
      pfrag[cg * 2]     = ua.v8;   // keys cg*32 + 0..15
      pfrag[cg * 2 + 1] = ub.v8;   // keys cg*32 + 16..31
    }

    // PV: ctx[ng] += P[q][key] * V[key][d],  d = ng*32 + l31
    __builtin_amdgcn_s_setprio(1);
#pragma unroll
    for (int ng = 0; ng < 4; ng++) {
      const int drow = ng * 32 + l31;
#pragma unroll
      for (int kc = 0; kc < 4; kc++) {
        bf16x8 vf = *reinterpret_cast<const bf16x8*>(vsc + drow * 64 + (((kc * 2 + hi) ^ (l31 & 7)) * 8));
        ctx[ng] = __builtin_amdgcn_mfma_f32_32x32x16_bf16(pfrag[kc], vf, ctx[ng], 0, 0, 0);
      }
    }
    __builtin_amdgcn_s_setprio(0);

    // stage next tile into the OTHER buffer; single barrier orders everything
    if (kt + 1 < nkt) {
#pragma unroll
      for (int p2 = 0; p2 < 2; p2++) {
        const int row = kr + 32 * p2;
        *reinterpret_cast<uint4*>(ksn + row * 128 + ((kc16 ^ (row & 15)) * 8)) = kreg[p2];
        const int d = vd + 64 * p2;
        *reinterpret_cast<uint4*>(vsn + d * 64 + ((vc8 ^ (d & 7)) * 8)) = vreg[p2];
      }
      __syncthreads();
    }
  }

  // epilogue: combine l across hi halves, broadcast 1/l via shuffles
  {
    float lt  = lsum + __shfl_xor(lsum, 32);
    float inv = 1.0f / lt;
    float il[16];
#pragma unroll
    for (int r = 0; r < 16; r++)
      il[r] = __shfl(inv, (r & 3) + 8 * (r >> 2) + 4 * hi);
    const size_t orow0 = bS + qb + rg * 32;
#pragma unroll
    for (int ng = 0; ng < 4; ng++)
#pragma unroll
      for (int r = 0; r < 16; r++) {
        const int qp = (r & 3) + 8 * (r >> 2) + 4 * hi;
        O[(orow0 + qp) * (NH_ * HD_) + h * HD_ + ng * 32 + l31] = f2b(ctx[ng][r] * il[r]);
      }
  }
}

// ---------------------------------------------------------------------------
// Launcher. Big path (ws >= ~54.5 MB): pre-convert x + weights to bf16 in ws,
// all GEMMs via gemm_ld (global_load_lds). Fallback: exact round-8 pipeline.
// d_out head holds Kb/Vb/VT (12 MB), consumed before final GEMM overwrites out.
// ---------------------------------------------------------------------------
extern "C" void kernel_launch(void* const* d_in, const int* in_sizes, int n_in,
                              void* d_out, int out_size, void* d_ws, size_t ws_size,
                              hipStream_t stream) {
  const float* x    = (const float*)d_in[0];
  const float* Wq   = (const float*)d_in[1];
  const float* Wk   = (const float*)d_in[2];
  const float* Wv   = (const float*)d_in[3];
  const float* Wo   = (const float*)d_in[4];
  const float* cosT = (const float*)d_in[5];
  const float* sinT = (const float*)d_in[6];
  float* out = (float*)d_out;

  const size_t qElems  = (size_t)M_ * NH_ * HD_;   // 8.39 M
  const size_t xElems  = (size_t)M_ * H_;          // 8.39 M
  const size_t wqElems = (size_t)H_ * H_;          // 4.19 M
  const size_t wkElems = (size_t)NKV_ * HD_ * H_;  // 1.05 M
  const size_t bigNeed = (qElems + xElems + 2 * wqElems + 2 * wkElems) * 2 + 256;

  if (ws_size < qElems * 2 + 256) return;

  unsigned short* Qb = (unsigned short*)d_ws;
  unsigned short* Kb = (unsigned short*)d_out;
  unsigned short* Vb = Kb + (size_t)M_ * NKV_ * HD_;
  unsigned short* VT = Vb + (size_t)M_ * NKV_ * HD_;

  dim3 blk(256);
  const int rope_threads = M_ * (NH_ + NKV_) * 64;

  if (ws_size >= bigNeed) {
    unsigned short* xb  = Qb + qElems;
    unsigned short* Wqb = xb + xElems;
    unsigned short* Wob = Wqb + wqElems;
    unsigned short* Wkb = Wob + wqElems;
    unsigned short* Wvb = Wkb + wkElems;

    cvt_bf16<<<dim3((int)(xElems / 8 + 255) / 256), blk, 0, stream>>>(x,  xb,  (int)(xElems / 8));
    cvt_bf16<<<dim3((int)(wqElems / 8 + 255) / 256), blk, 0, stream>>>(Wq, Wqb, (int)(wqElems / 8));
    cvt_bf16<<<dim3((int)(wkElems / 8 + 255) / 256), blk, 0, stream>>>(Wk, Wkb, (int)(wkElems / 8));
    cvt_bf16<<<dim3((int)(wkElems / 8 + 255) / 256), blk, 0, stream>>>(Wv, Wvb, (int)(wkElems / 8));
    cvt_bf16<<<dim3((int)(wqElems / 8 + 255) / 256), blk, 0, stream>>>(Wo, Wob, (int)(wqElems / 8));

    gemm_ld<false><<<dim3(16, 32), blk, 0, stream>>>(xb, Wqb, Wqb, Qb, Qb, NH_ * HD_, H_, 16);
    gemm_ld<false><<<dim3(8, 32), blk, 0, stream>>>(xb, Wkb, Wvb, Kb, Vb, NKV_ * HD_, H_, 4);

    rope_k<<<dim3((rope_threads + 255) / 256), blk, 0, stream>>>(Qb, Kb, cosT, sinT);
    transp_v<<<dim3(M_ / 64, (NKV_ * HD_) / 64), blk, 0, stream>>>(Vb, VT);
    attn<<<dim3(32, NKV_, B_), dim3(512), 0, stream>>>(Qb, Kb, VT, Qb);

    gemm_ld<true><<<dim3(16, 32), blk, 0, stream>>>(Qb, Wob, Wob, out, out, H_, NH_ * HD_, 16);
  } else {
    gemm_k<false><<<dim3(16, 32), blk, 0, stream>>>(x, Wq, Wq, Qb, Qb, NH_ * HD_, H_, 16);
    gemm_k<false><<<dim3(8, 32), blk, 0, stream>>>(x, Wk, Wv, Kb, Vb, NKV_ * HD_, H_, 4);

    rope_k<<<dim3((rope_threads + 255) / 256), blk, 0, stream>>>(Qb, Kb, cosT, sinT);
    transp_v<<<dim3(M_ / 64, (NKV_ * HD_) / 64), blk, 0, stream>>>(Vb, VT);
    attn<<<dim3(32, NKV_, B_), dim3(512), 0, stream>>>(Qb, Kb, VT, Qb);

    gemm_k<true><<<dim3(16, 32), blk, 0, stream>>>(Qb, Wo, Wo, out, out, H_, NH_ * HD_, 16);
  }
}

// Round 7
// 321.715 us; speedup vs baseline: 1.3582x; 1.1337x over previous
//
#include <hip/hip_runtime.h>
#include <stdint.h>

#define B_   2
#define S_   2048
#define H_   2048
#define NH_  16
#define NKV_ 4
#define HD_  128
#define M_   (B_ * S_)   // 4096

typedef short bf16x8 __attribute__((ext_vector_type(8)));
typedef float f32x4  __attribute__((ext_vector_type(4)));
typedef float f32x16 __attribute__((ext_vector_type(16)));

__device__ __forceinline__ float b2f(unsigned short u) {
  union { unsigned int u; float f; } v; v.u = ((unsigned int)u) << 16; return v.f;
}
__device__ __forceinline__ unsigned short f2b(float f) {
  union { float f; unsigned int u; } v; v.f = f;
  unsigned int u = v.u;
  unsigned int r = (u + 0x7FFFu + ((u >> 16) & 1u)) >> 16;
  return (unsigned short)r;
}
__device__ __forceinline__ uint4 pack8(const float4& a, const float4& b) {
  uint4 r;
  r.x = (unsigned)f2b(a.x) | ((unsigned)f2b(a.y) << 16);
  r.y = (unsigned)f2b(a.z) | ((unsigned)f2b(a.w) << 16);
  r.z = (unsigned)f2b(b.x) | ((unsigned)f2b(b.y) << 16);
  r.w = (unsigned)f2b(b.z) | ((unsigned)f2b(b.w) << 16);
  return r;
}
// async global -> LDS, 16 B per lane; dest = lds base (wave-uniform) + lane*16
__device__ __forceinline__ void gload_lds(const unsigned short* g, unsigned short* l) {
  __builtin_amdgcn_global_load_lds(
      (const __attribute__((address_space(1))) unsigned int*)g,
      (__attribute__((address_space(3))) unsigned int*)l, 16, 0, 0);
}

// ---------------------------------------------------------------------------
// Fused f32 -> bf16 convert for x, Wq, Wk, Wv, Wo in ONE launch (was 5).
// ---------------------------------------------------------------------------
__global__ void cvt_all(const float* __restrict__ x,  unsigned short* __restrict__ xb,
                        const float* __restrict__ wq, unsigned short* __restrict__ wqb,
                        const float* __restrict__ wk, unsigned short* __restrict__ wkb,
                        const float* __restrict__ wv, unsigned short* __restrict__ wvb,
                        const float* __restrict__ wo, unsigned short* __restrict__ wob)
{
  const int n8x = (M_ * H_) / 8;          // 1048576
  const int n8q = (H_ * H_) / 8;          // 524288
  const int n8k = (NKV_ * HD_ * H_) / 8;  // 131072
  int i = blockIdx.x * blockDim.x + threadIdx.x;
  const float* s; unsigned short* d; int off;
  if (i < n8x)                         { s = x;  d = xb;  off = i; }
  else if (i < n8x + n8q)              { s = wq; d = wqb; off = i - n8x; }
  else if (i < n8x + n8q + n8k)        { s = wk; d = wkb; off = i - n8x - n8q; }
  else if (i < n8x + n8q + 2 * n8k)    { s = wv; d = wvb; off = i - n8x - n8q - n8k; }
  else if (i < n8x + 2 * n8q + 2 * n8k){ s = wo; d = wob; off = i - n8x - n8q - 2 * n8k; }
  else return;
  const float* p = s + (size_t)off * 8;
  uint4 v = pack8(*reinterpret_cast<const float4*>(p), *reinterpret_cast<const float4*>(p + 4));
  *reinterpret_cast<uint4*>(d + (size_t)off * 8) = v;
}

// ---------------------------------------------------------------------------
// gemm_qkv: one launch computing Q = xb@Wq^T [4096x2048], K = xb@Wk^T and
// V = xb@Wv^T [4096x512]. Same tile body as gemm_ld; 3-way output select:
// blockIdx.x < 16 -> (Wq, Qb, N=2048); 16..19 -> (Wk, Kb, N=512);
// 20..23 -> (Wv, Vb, N=512). Grid (24, 32) = 768 blocks (KV fills CUs
// alongside Q instead of a separate underfilled 256-block launch).
// ---------------------------------------------------------------------------
__global__ __launch_bounds__(256, 4) void gemm_qkv(
    const unsigned short* __restrict__ A, const unsigned short* __restrict__ Wq,
    const unsigned short* __restrict__ Wk, const unsigned short* __restrict__ Wv,
    unsigned short* __restrict__ Qo, unsigned short* __restrict__ Ko,
    unsigned short* __restrict__ Vo)
{
  __shared__ unsigned short As[128 * 64];
  __shared__ unsigned short Bs[128 * 64];

  const int K = H_;                      // 2048 (inner dim for all three)
  const unsigned short* Bm; unsigned short* Cm; int colBase, N;
  const int bx = blockIdx.x;
  if (bx < 16)      { Bm = Wq; Cm = Qo; colBase = bx * 128;        N = NH_ * HD_;  }
  else if (bx < 20) { Bm = Wk; Cm = Ko; colBase = (bx - 16) * 128; N = NKV_ * HD_; }
  else              { Bm = Wv; Cm = Vo; colBase = (bx - 20) * 128; N = NKV_ * HD_; }
  const int rowBase = blockIdx.y * 128;

  const int tid    = threadIdx.x;
  const int lane   = tid & 63;
  const int wid    = tid >> 6;
  const int wrow   = wid >> 1;
  const int wcol   = wid & 1;
  const int lane15 = lane & 15;
  const int quad   = lane >> 4;

  const f32x4 zero = {0.f, 0.f, 0.f, 0.f};
  f32x4 acc[4][4];
#pragma unroll
  for (int i = 0; i < 4; i++)
#pragma unroll
    for (int j = 0; j < 4; j++) acc[i][j] = zero;

  const int lr  = lane >> 3;
  const int sc8 = (lane & 7) ^ lr;

  for (int kb = 0; kb < K; kb += 64) {
    __syncthreads();
#pragma unroll
    for (int i = 0; i < 4; i++) {
      const int rg = (i * 4 + wid) * 8;
      const int r  = rg + lr;
      gload_lds(A  + (size_t)(rowBase + r) * K + kb + sc8 * 8, As + rg * 64);
      gload_lds(Bm + (size_t)(colBase + r) * K + kb + sc8 * 8, Bs + rg * 64);
    }
    __syncthreads();
#pragma unroll
    for (int kc = 0; kc < 2; kc++) {
      bf16x8 af[4], bf[4];
#pragma unroll
      for (int g = 0; g < 4; g++) {
        const int ra = wrow * 64 + g * 16 + lane15;
        const int rb = wcol * 64 + g * 16 + lane15;
        af[g] = *reinterpret_cast<const bf16x8*>(As + ra * 64 + (((kc * 4 + quad) ^ (ra & 7)) * 8));
        bf[g] = *reinterpret_cast<const bf16x8*>(Bs + rb * 64 + (((kc * 4 + quad) ^ (rb & 7)) * 8));
      }
#pragma unroll
      for (int i = 0; i < 4; i++)
#pragma unroll
        for (int j = 0; j < 4; j++)
          acc[i][j] = __builtin_amdgcn_mfma_f32_16x16x32_bf16(af[i], bf[j], acc[i][j], 0, 0, 0);
    }
  }

#pragma unroll
  for (int i = 0; i < 4; i++) {
    int row = rowBase + wrow * 64 + i * 16 + quad * 4;
#pragma unroll
    for (int j = 0; j < 4; j++) {
      int col = colBase + wcol * 64 + j * 16 + lane15;
#pragma unroll
      for (int rr = 0; rr < 4; rr++)
        Cm[(size_t)(row + rr) * N + col] = f2b(acc[i][j][rr]);
    }
  }
}

// ---------------------------------------------------------------------------
// gemm_ld: C[M,N] = A[M,K] @ B[N,K]^T, all-bf16 inputs, f32 acc.
// m97-style: 128x128 tile, BK=64, global_load_lds width=16 staging,
// XOR-swizzled LDS. Dual-output; CF32: f32 C. (Used for the O-projection.)
// ---------------------------------------------------------------------------
template<bool CF32>
__global__ __launch_bounds__(256, 4) void gemm_ld(
    const unsigned short* __restrict__ A, const unsigned short* __restrict__ B0,
    const unsigned short* __restrict__ B1, void* __restrict__ C0, void* __restrict__ C1,
    int N, int K, int nxHalf)
{
  __shared__ unsigned short As[128 * 64];
  __shared__ unsigned short Bs[128 * 64];

  const unsigned short* Bm; void* Cm; int colBase;
  if ((int)blockIdx.x < nxHalf) { Bm = B0; Cm = C0; colBase = blockIdx.x * 128; }
  else                          { Bm = B1; Cm = C1; colBase = (blockIdx.x - nxHalf) * 128; }
  const int rowBase = blockIdx.y * 128;

  const int tid    = threadIdx.x;
  const int lane   = tid & 63;
  const int wid    = tid >> 6;
  const int wrow   = wid >> 1;
  const int wcol   = wid & 1;
  const int lane15 = lane & 15;
  const int quad   = lane >> 4;

  const f32x4 zero = {0.f, 0.f, 0.f, 0.f};
  f32x4 acc[4][4];
#pragma unroll
  for (int i = 0; i < 4; i++)
#pragma unroll
    for (int j = 0; j < 4; j++) acc[i][j] = zero;

  const int lr  = lane >> 3;
  const int sc8 = (lane & 7) ^ lr;

  for (int kb = 0; kb < K; kb += 64) {
    __syncthreads();
#pragma unroll
    for (int i = 0; i < 4; i++) {
      const int rg = (i * 4 + wid) * 8;
      const int r  = rg + lr;
      gload_lds(A  + (size_t)(rowBase + r) * K + kb + sc8 * 8, As + rg * 64);
      gload_lds(Bm + (size_t)(colBase + r) * K + kb + sc8 * 8, Bs + rg * 64);
    }
    __syncthreads();
#pragma unroll
    for (int kc = 0; kc < 2; kc++) {
      bf16x8 af[4], bf[4];
#pragma unroll
      for (int g = 0; g < 4; g++) {
        const int ra = wrow * 64 + g * 16 + lane15;
        const int rb = wcol * 64 + g * 16 + lane15;
        af[g] = *reinterpret_cast<const bf16x8*>(As + ra * 64 + (((kc * 4 + quad) ^ (ra & 7)) * 8));
        bf[g] = *reinterpret_cast<const bf16x8*>(Bs + rb * 64 + (((kc * 4 + quad) ^ (rb & 7)) * 8));
      }
#pragma unroll
      for (int i = 0; i < 4; i++)
#pragma unroll
        for (int j = 0; j < 4; j++)
          acc[i][j] = __builtin_amdgcn_mfma_f32_16x16x32_bf16(af[i], bf[j], acc[i][j], 0, 0, 0);
    }
  }

  if (CF32) {
    float* Cf = (float*)Cm;
#pragma unroll
    for (int i = 0; i < 4; i++) {
      int row = rowBase + wrow * 64 + i * 16 + quad * 4;
#pragma unroll
      for (int j = 0; j < 4; j++) {
        int col = colBase + wcol * 64 + j * 16 + lane15;
#pragma unroll
        for (int rr = 0; rr < 4; rr++)
          Cf[(size_t)(row + rr) * N + col] = acc[i][j][rr];
      }
    }
  } else {
    unsigned short* Cb = (unsigned short*)Cm;
#pragma unroll
    for (int i = 0; i < 4; i++) {
      int row = rowBase + wrow * 64 + i * 16 + quad * 4;
#pragma unroll
      for (int j = 0; j < 4; j++) {
        int col = colBase + wcol * 64 + j * 16 + lane15;
#pragma unroll
        for (int rr = 0; rr < 4; rr++)
          Cb[(size_t)(row + rr) * N + col] = f2b(acc[i][j][rr]);
      }
    }
  }
}

// ---------------------------------------------------------------------------
// Fallback GEMM (round-8 proven): VGPR-roundtrip staging, f32 B packed at load.
// ---------------------------------------------------------------------------
template<bool OPROJ>
__global__ __launch_bounds__(256, 3) void gemm_k(
    const void* __restrict__ A, const float* __restrict__ B0, const float* __restrict__ B1,
    void* __restrict__ C0, void* __restrict__ C1, int N, int K, int nxHalf)
{
  __shared__ unsigned short As[128 * 72];
  __shared__ unsigned short Bs[128 * 72];

  const float* Bm; void* Cm; int colBase;
  if ((int)blockIdx.x < nxHalf) { Bm = B0; Cm = C0; colBase = blockIdx.x * 128; }
  else                          { Bm = B1; Cm = C1; colBase = (blockIdx.x - nxHalf) * 128; }
  const int rowBase = blockIdx.y * 128;

  const int tid    = threadIdx.x;
  const int lane   = tid & 63;
  const int wid    = tid >> 6;
  const int wrow   = wid >> 1;
  const int wcol   = wid & 1;
  const int lane15 = lane & 15;
  const int quad   = lane >> 4;

  const f32x4 zero = {0.f, 0.f, 0.f, 0.f};
  f32x4 acc[4][4];
#pragma unroll
  for (int i = 0; i < 4; i++)
#pragma unroll
    for (int j = 0; j < 4; j++) acc[i][j] = zero;

  const int r0 = tid >> 3;
  const int c8 = tid & 7;

  uint4 av[4], bv[4];
#pragma unroll
  for (int p = 0; p < 4; p++) {
    int r = r0 + 32 * p;
    if (OPROJ) {
      av[p] = *reinterpret_cast<const uint4*>((const unsigned short*)A + (size_t)(rowBase + r) * K + c8 * 8);
    } else {
      const float* pA = (const float*)A + (size_t)(rowBase + r) * K + c8 * 8;
      av[p] = pack8(*reinterpret_cast<const float4*>(pA), *reinterpret_cast<const float4*>(pA + 4));
    }
    const float* pB = Bm + (size_t)(colBase + r) * K + c8 * 8;
    bv[p] = pack8(*reinterpret_cast<const float4*>(pB), *reinterpret_cast<const float4*>(pB + 4));
  }

  for (int kb = 0; kb < K; kb += 64) {
    __syncthreads();
#pragma unroll
    for (int p = 0; p < 4; p++) {
      int r = r0 + 32 * p;
      *reinterpret_cast<uint4*>(As + r * 72 + c8 * 8) = av[p];
      *reinterpret_cast<uint4*>(Bs + r * 72 + c8 * 8) = bv[p];
    }
    __syncthreads();
    const int kn = kb + 64;
    if (kn < K) {
#pragma unroll
      for (int p = 0; p < 4; p++) {
        int r = r0 + 32 * p;
        if (OPROJ) {
          av[p] = *reinterpret_cast<const uint4*>((const unsigned short*)A + (size_t)(rowBase + r) * K + kn + c8 * 8);
        } else {
          const float* pA = (const float*)A + (size_t)(rowBase + r) * K + kn + c8 * 8;
          av[p] = pack8(*reinterpret_cast<const float4*>(pA), *reinterpret_cast<const float4*>(pA + 4));
        }
        const float* pB = Bm + (size_t)(colBase + r) * K + kn + c8 * 8;
        bv[p] = pack8(*reinterpret_cast<const float4*>(pB), *reinterpret_cast<const float4*>(pB + 4));
      }
    }
#pragma unroll
    for (int kc = 0; kc < 2; kc++) {
      bf16x8 af[4], bf[4];
#pragma unroll
      for (int g = 0; g < 4; g++) {
        af[g] = *reinterpret_cast<const bf16x8*>(As + (wrow * 64 + g * 16 + lane15) * 72 + kc * 32 + quad * 8);
        bf[g] = *reinterpret_cast<const bf16x8*>(Bs + (wcol * 64 + g * 16 + lane15) * 72 + kc * 32 + quad * 8);
      }
#pragma unroll
      for (int i = 0; i < 4; i++)
#pragma unroll
        for (int j = 0; j < 4; j++)
          acc[i][j] = __builtin_amdgcn_mfma_f32_16x16x32_bf16(af[i], bf[j], acc[i][j], 0, 0, 0);
    }
  }

  if (OPROJ) {
    float* Cf = (float*)Cm;
#pragma unroll
    for (int i = 0; i < 4; i++) {
      int row = rowBase + wrow * 64 + i * 16 + quad * 4;
#pragma unroll
      for (int j = 0; j < 4; j++) {
        int col = colBase + wcol * 64 + j * 16 + lane15;
#pragma unroll
        for (int rr = 0; rr < 4; rr++)
          Cf[(size_t)(row + rr) * N + col] = acc[i][j][rr];
      }
    }
  } else {
    unsigned short* Cb = (unsigned short*)Cm;
#pragma unroll
    for (int i = 0; i < 4; i++) {
      int row = rowBase + wrow * 64 + i * 16 + quad * 4;
#pragma unroll
      for (int j = 0; j < 4; j++) {
        int col = colBase + wcol * 64 + j * 16 + lane15;
#pragma unroll
        for (int rr = 0; rr < 4; rr++)
          Cb[(size_t)(row + rr) * N + col] = f2b(acc[i][j][rr]);
      }
    }
  }
}

// ---------------------------------------------------------------------------
// RoPE in-place on bf16 Q [M, 2048] and K [M, 512]; cos/sin f32.
// ---------------------------------------------------------------------------
__global__ void rope_k(unsigned short* __restrict__ Qb, unsigned short* __restrict__ Kb,
                       const float* __restrict__ cosT, const float* __restrict__ sinT)
{
  const int per_tok = (NH_ + NKV_) * 64;
  int idx = blockIdx.x * blockDim.x + threadIdx.x;
  int t = idx / per_tok;
  int r = idx - t * per_tok;
  if (t >= M_) return;
  int s = t & (S_ - 1);
  unsigned short* base;
  int d;
  if (r < NH_ * 64) {
    int h = r >> 6; d = r & 63;
    base = Qb + (size_t)t * (NH_ * HD_) + h * HD_ + d;
  } else {
    int rk = r - NH_ * 64;
    int h = rk >> 6; d = rk & 63;
    base = Kb + (size_t)t * (NKV_ * HD_) + h * HD_ + d;
  }
  float c  = cosT[s * HD_ + d];
  float sn = sinT[s * HD_ + d];
  float x0 = b2f(base[0]);
  float x1 = b2f(base[64]);
  base[0]  = f2b(x0 * c - x1 * sn);
  base[64] = f2b(x1 * c + x0 * sn);
}

// ---------------------------------------------------------------------------
// V transpose: Vb[M,512] -> VT[B*512, 2048] (dim-major). 64x64 LDS tiles.
// ---------------------------------------------------------------------------
__global__ void transp_v(const unsigned short* __restrict__ Vb, unsigned short* __restrict__ VT)
{
  __shared__ unsigned short Ls[64 * 72];
  const int t0 = blockIdx.x * 64;
  const int d0 = blockIdx.y * 64;
  const int tid = threadIdx.x;
  const int r = tid >> 3, c = tid & 7;
#pragma unroll
  for (int p = 0; p < 2; p++)
    *reinterpret_cast<uint4*>(Ls + (r + 32 * p) * 72 + c * 8) =
      *reinterpret_cast<const uint4*>(Vb + (size_t)(t0 + r + 32 * p) * (NKV_ * HD_) + d0 + c * 8);
  __syncthreads();
  const int bq = t0 >> 11, s0 = t0 & (S_ - 1);
#pragma unroll
  for (int p = 0; p < 2; p++) {
    int dl = r + 32 * p;
    unsigned short tmp[8];
#pragma unroll
    for (int j = 0; j < 8; j++) tmp[j] = Ls[(c * 8 + j) * 72 + dl];
    *reinterpret_cast<uint4*>(VT + (size_t)(bq * 512 + d0 + dl) * S_ + s0 + c * 8) =
      *reinterpret_cast<uint4*>(tmp);
  }
}

// ---------------------------------------------------------------------------
// Flash attention v8 (round-5 VERIFIED, restored verbatim): 32x32x16 swapped-QK
// + in-register softmax (T12) + double-buffered K/V LDS, ONE barrier per
// iteration. One q-tile per block (g = blockIdx.x, nkt = g+1), alias-safe.
// ---------------------------------------------------------------------------
__global__ __launch_bounds__(512, 1) void attn(
    const unsigned short* __restrict__ Q, const unsigned short* __restrict__ Kc,
    const unsigned short* __restrict__ VT, unsigned short* __restrict__ O)
{
  __shared__ unsigned short KsA[2 * 64 * 128];   // [buf][key][hd], chunk16B ^= (key&15)
  __shared__ unsigned short VsA[2 * 128 * 64];   // [buf][dim][key], chunk16B ^= (dim&7)

  const int tid  = threadIdx.x;
  const int lane = tid & 63;
  const int w    = tid >> 6;
  const int l31  = lane & 31;
  const int hi   = lane >> 5;
  const int g    = blockIdx.x;            // q-tile 0..31
  const int kvh  = blockIdx.y;
  const int b    = blockIdx.z;
  const int h    = kvh * 4 + (w & 3);
  const int rg   = w >> 2;                // 0..1: rows rg*32..rg*32+31
  const size_t bS = (size_t)b * S_;
  const int nkt  = g + 1;
  const int qb   = g * 64;

  const int kr   = tid >> 4;
  const int kc16 = tid & 15;
  const int vd   = tid >> 3;
  const int vc8  = tid & 7;

  const unsigned short* Kbase = Kc + bS * (NKV_ * HD_) + kvh * HD_;
  const unsigned short* Vbase = VT + (size_t)(b * 512 + kvh * HD_) * S_;

  bf16x8 qf[8];
  {
    const unsigned short* qp = Q + (bS + qb + rg * 32 + l31) * (NH_ * HD_) + h * HD_ + hi * 8;
#pragma unroll
    for (int kc = 0; kc < 8; kc++) qf[kc] = *reinterpret_cast<const bf16x8*>(qp + kc * 16);
  }

  f32x16 ctx[4];
#pragma unroll
  for (int ng = 0; ng < 4; ng++)
#pragma unroll
    for (int r = 0; r < 16; r++) ctx[ng][r] = 0.f;
  float lsum = 0.f;

  const float scale = 0.08838834764831845f;

  uint4 kreg[2], vreg[2];
#pragma unroll
  for (int p2 = 0; p2 < 2; p2++) {
    kreg[p2] = *reinterpret_cast<const uint4*>(Kbase + (size_t)(kr + 32 * p2) * (NKV_ * HD_) + kc16 * 8);
    vreg[p2] = *reinterpret_cast<const uint4*>(Vbase + (size_t)(vd + 64 * p2) * S_ + vc8 * 8);
  }
#pragma unroll
  for (int p2 = 0; p2 < 2; p2++) {
    const int row = kr + 32 * p2;
    *reinterpret_cast<uint4*>(KsA + row * 128 + ((kc16 ^ (row & 15)) * 8)) = kreg[p2];
    const int d = vd + 64 * p2;
    *reinterpret_cast<uint4*>(VsA + d * 64 + ((vc8 ^ (d & 7)) * 8)) = vreg[p2];
  }
  __syncthreads();

  for (int kt = 0; kt < nkt; kt++) {
    unsigned short* ksc = KsA + (kt & 1) * 8192;
    unsigned short* vsc = VsA + (kt & 1) * 8192;
    unsigned short* ksn = KsA + ((kt & 1) ^ 1) * 8192;
    unsigned short* vsn = VsA + ((kt & 1) ^ 1) * 8192;

    if (kt + 1 < nkt) {
      const int key0 = (kt + 1) * 64;
#pragma unroll
      for (int p2 = 0; p2 < 2; p2++) {
        kreg[p2] = *reinterpret_cast<const uint4*>(Kbase + (size_t)(key0 + kr + 32 * p2) * (NKV_ * HD_) + kc16 * 8);
        vreg[p2] = *reinterpret_cast<const uint4*>(Vbase + (size_t)(vd + 64 * p2) * S_ + key0 + vc8 * 8);
      }
    }

    f32x16 sc0, sc1;
#pragma unroll
    for (int r = 0; r < 16; r++) { sc0[r] = 0.f; sc1[r] = 0.f; }
    __builtin_amdgcn_s_setprio(1);
#pragma unroll
    for (int kc = 0; kc < 8; kc++) {
      const int ch = ((kc * 2 + hi) ^ (l31 & 15)) * 8;
      bf16x8 kf0 = *reinterpret_cast<const bf16x8*>(ksc + l31 * 128 + ch);
      sc0 = __builtin_amdgcn_mfma_f32_32x32x16_bf16(kf0, qf[kc], sc0, 0, 0, 0);
      bf16x8 kf1 = *reinterpret_cast<const bf16x8*>(ksc + (32 + l31) * 128 + ch);
      sc1 = __builtin_amdgcn_mfma_f32_32x32x16_bf16(kf1, qf[kc], sc1, 0, 0, 0);
    }
    __builtin_amdgcn_s_setprio(0);

    const int lim = (kt == nkt - 1) ? (rg * 32 + l31) : 4096;
    bf16x8 pfrag[4];
#pragma unroll
    for (int cg = 0; cg < 2; cg++) {
      float pe[16];
#pragma unroll
      for (int r = 0; r < 16; r++) {
        float v = (cg ? sc1[r] : sc0[r]) * scale;
        const int kp = cg * 32 + (r & 3) + 8 * (r >> 2) + 4 * hi;
        v = (kp <= lim) ? v : -1.0e9f;
        float e = __expf(v);
        pe[r] = e;
        lsum += e;
      }
      unsigned wd[8];
#pragma unroll
      for (int j = 0; j < 8; j++) {
        unsigned t;
        asm("v_cvt_pk_bf16_f32 %0, %1, %2" : "=v"(t) : "v"(pe[2 * j]), "v"(pe[2 * j + 1]));
        wd[j] = t;
      }
      asm("v_permlane32_swap_b32 %0, %1" : "+v"(wd[0]), "+v"(wd[2]));
      asm("v_permlane32_swap_b32 %0, %1" : "+v"(wd[1]), "+v"(wd[3]));
      asm("v_permlane32_swap_b32 %0, %1" : "+v"(wd[4]), "+v"(wd[6]));
      asm("v_permlane32_swap_b32 %0, %1" : "+v"(wd[5]), "+v"(wd[7]));
      union { unsigned u[4]; bf16x8 v8; } ua, ub;
      ua.u[0] = wd[0]; ua.u[1] = wd[1]; ua.u[2] = wd[2]; ua.u[3] = wd[3];
      ub.u[0] = wd[4]; ub.u[1] = wd[5]; ub.u[2] = wd[6]; ub.u[3] = wd[7];
      pfrag[cg * 2]     = ua.v8;
      pfrag[cg * 2 + 1] = ub.v8;
    }

    __builtin_amdgcn_s_setprio(1);
#pragma unroll
    for (int ng = 0; ng < 4; ng++) {
      const int drow = ng * 32 + l31;
#pragma unroll
      for (int kc = 0; kc < 4; kc++) {
        bf16x8 vf = *reinterpret_cast<const bf16x8*>(vsc + drow * 64 + (((kc * 2 + hi) ^ (l31 & 7)) * 8));
        ctx[ng] = __builtin_amdgcn_mfma_f32_32x32x16_bf16(pfrag[kc], vf, ctx[ng], 0, 0, 0);
      }
    }
    __builtin_amdgcn_s_setprio(0);

    if (kt + 1 < nkt) {
#pragma unroll
      for (int p2 = 0; p2 < 2; p2++) {
        const int row = kr + 32 * p2;
        *reinterpret_cast<uint4*>(ksn + row * 128 + ((kc16 ^ (row & 15)) * 8)) = kreg[p2];
        const int d = vd + 64 * p2;
        *reinterpret_cast<uint4*>(vsn + d * 64 + ((vc8 ^ (d & 7)) * 8)) = vreg[p2];
      }
      __syncthreads();
    }
  }

  {
    float lt  = lsum + __shfl_xor(lsum, 32);
    float inv = 1.0f / lt;
    float il[16];
#pragma unroll
    for (int r = 0; r < 16; r++)
      il[r] = __shfl(inv, (r & 3) + 8 * (r >> 2) + 4 * hi);
    const size_t orow0 = bS + qb + rg * 32;
#pragma unroll
    for (int ng = 0; ng < 4; ng++)
#pragma unroll
      for (int r = 0; r < 16; r++) {
        const int qp = (r & 3) + 8 * (r >> 2) + 4 * hi;
        O[(orow0 + qp) * (NH_ * HD_) + h * HD_ + ng * 32 + l31] = f2b(ctx[ng][r] * il[r]);
      }
  }
}

// ---------------------------------------------------------------------------
// Launcher. Big path: cvt_all -> gemm_qkv (fused QKV projections) -> rope ->
// transp_v -> attn (v8) -> gemm_ld O-projection. Fallback: round-8 pipeline.
// ---------------------------------------------------------------------------
extern "C" void kernel_launch(void* const* d_in, const int* in_sizes, int n_in,
                              void* d_out, int out_size, void* d_ws, size_t ws_size,
                              hipStream_t stream) {
  const float* x    = (const float*)d_in[0];
  const float* Wq   = (const float*)d_in[1];
  const float* Wk   = (const float*)d_in[2];
  const float* Wv   = (const float*)d_in[3];
  const float* Wo   = (const float*)d_in[4];
  const float* cosT = (const float*)d_in[5];
  const float* sinT = (const float*)d_in[6];
  float* out = (float*)d_out;

  const size_t qElems  = (size_t)M_ * NH_ * HD_;   // 8.39 M
  const size_t xElems  = (size_t)M_ * H_;          // 8.39 M
  const size_t wqElems = (size_t)H_ * H_;          // 4.19 M
  const size_t wkElems = (size_t)NKV_ * HD_ * H_;  // 1.05 M
  const size_t bigNeed = (qElems + xElems + 2 * wqElems + 2 * wkElems) * 2 + 256;

  if (ws_size < qElems * 2 + 256) return;

  unsigned short* Qb = (unsigned short*)d_ws;
  unsigned short* Kb = (unsigned short*)d_out;
  unsigned short* Vb = Kb + (size_t)M_ * NKV_ * HD_;
  unsigned short* VT = Vb + (size_t)M_ * NKV_ * HD_;

  dim3 blk(256);
  const int rope_threads = M_ * (NH_ + NKV_) * 64;

  if (ws_size >= bigNeed) {
    unsigned short* xb  = Qb + qElems;
    unsigned short* Wqb = xb + xElems;
    unsigned short* Wob = Wqb + wqElems;
    unsigned short* Wkb = Wob + wqElems;
    unsigned short* Wvb = Wkb + wkElems;

    const int n8tot = (int)((xElems + 2 * wqElems + 2 * wkElems) / 8);
    cvt_all<<<dim3((n8tot + 255) / 256), blk, 0, stream>>>(
        x, xb, Wq, Wqb, Wk, Wkb, Wv, Wvb, Wo, Wob);

    gemm_qkv<<<dim3(24, 32), blk, 0, stream>>>(xb, Wqb, Wkb, Wvb, Qb, Kb, Vb);

    rope_k<<<dim3((rope_threads + 255) / 256), blk, 0, stream>>>(Qb, Kb, cosT, sinT);
    transp_v<<<dim3(M_ / 64, (NKV_ * HD_) / 64), blk, 0, stream>>>(Vb, VT);
    attn<<<dim3(32, NKV_, B_), dim3(512), 0, stream>>>(Qb, Kb, VT, Qb);

    gemm_ld<true><<<dim3(16, 32), blk, 0, stream>>>(Qb, Wob, Wob, out, out, H_, NH_ * HD_, 16);
  } else {
    gemm_k<false><<<dim3(16, 32), blk, 0, stream>>>(x, Wq, Wq, Qb, Qb, NH_ * HD_, H_, 16);
    gemm_k<false><<<dim3(8, 32), blk, 0, stream>>>(x, Wk, Wv, Kb, Vb, NKV_ * HD_, H_, 4);

    rope_k<<<dim3((rope_threads + 255) / 256), blk, 0, stream>>>(Qb, Kb, cosT, sinT);
    transp_v<<<dim3(M_ / 64, (NKV_ * HD_) / 64), blk, 0, stream>>>(Vb, VT);
    attn<<<dim3(32, NKV_, B_), dim3(512), 0, stream>>>(Qb, Kb, VT, Qb);

    gemm_k<true><<<dim3(16, 32), blk, 0, stream>>>(Qb, Wo, Wo, out, out, H_, NH_ * HD_, 16);
  }
}